// Round 1
// baseline (269.116 us; speedup 1.0000x reference)
//
#include <hip/hip_runtime.h>

#define NB 4
#define NC 8
#define NLOC 524288        // H*W*D = 128*128*32
#define TOPN 512
#define POST 100
#define NBIN 8192
#define CAP 8192
#define NMS_THR 0.6f
#define CAND_THR 0.05f

typedef unsigned long long ull;

// ---------------- workspace layout ----------------
// [0, 131072)            hist      : NB * NBIN * u32   (zeroed each call)
// [131072, 131088)       counts    : NB * u32          (zeroed each call)
// [131200, 147584)       topk      : NB * TOPN * u64   (zeroed each call)
// [147584, 147600)       cutoff    : NB * u32
// [147712, 409856)       keys      : NB * CAP * u64
// [409856, 459008)       det       : NB * TOPN * 6 f32
// [459008, 467200)       score     : NB * TOPN f32
// [467200, 475392)       clsid     : NB * TOPN i32
// [475392, 483584)       valid     : NB * TOPN i32
#define OFF_HIST   0
#define OFF_CNT    131072
#define OFF_TOPK   131200
#define OFF_CUT    147584
#define OFF_KEYS   147712
#define OFF_DET    409856
#define OFF_SCORE  459008
#define OFF_CLS    467200
#define OFF_VALID  475392
#define ZERO_BYTES 147584

__device__ __forceinline__ float sigmoidf_(float x) {
    return 1.0f / (1.0f + expf(-x));
}

// Pass 1: per-image histogram of candidate score bits (top 17 bits -> 8192 bins)
__global__ void hist_kernel(const float* __restrict__ cls,
                            const float* __restrict__ ctr,
                            unsigned int* __restrict__ hist) {
    __shared__ unsigned int lh[NBIN];
    const int b = blockIdx.y;
    for (int i = threadIdx.x; i < NBIN; i += blockDim.x) lh[i] = 0;
    __syncthreads();
    const int n = blockIdx.x * blockDim.x + threadIdx.x;
    if (n < NLOC) {
        const float sc = sigmoidf_(ctr[(size_t)b * NLOC + n]);
        const float* cp = cls + (size_t)b * NC * NLOC + n;
        #pragma unroll
        for (int c = 0; c < NC; ++c) {
            const float s = sigmoidf_(cp[(size_t)c * NLOC]);
            if (s > CAND_THR) {
                const unsigned bits = __float_as_uint(s * sc);
                atomicAdd(&lh[bits >> 17], 1u);
            }
        }
    }
    __syncthreads();
    for (int i = threadIdx.x; i < NBIN; i += blockDim.x)
        if (lh[i]) atomicAdd(&hist[b * NBIN + i], lh[i]);
}

// Pass 2: find cutoff bin per image (cumulative-from-top >= TOPN)
__global__ void cutoff_kernel(const unsigned int* __restrict__ hist,
                              unsigned int* __restrict__ cutoff) {
    const int b = blockIdx.x;
    if (threadIdx.x == 0) {
        unsigned cum = 0;
        int bin = 0;
        for (int i = NBIN - 1; i >= 0; --i) {
            cum += hist[b * NBIN + i];
            if (cum >= TOPN) { bin = i; break; }
        }
        cutoff[b] = (unsigned)bin;
    }
}

// Pass 3: gather packed keys for entries at/above cutoff bin
__global__ void gather_kernel(const float* __restrict__ cls,
                              const float* __restrict__ ctr,
                              const unsigned int* __restrict__ cutoff,
                              ull* __restrict__ keys,
                              unsigned int* __restrict__ counts) {
    const int b = blockIdx.y;
    const unsigned cb = cutoff[b];
    const int n = blockIdx.x * blockDim.x + threadIdx.x;
    if (n >= NLOC) return;
    const float sc = sigmoidf_(ctr[(size_t)b * NLOC + n]);
    const float* cp = cls + (size_t)b * NC * NLOC + n;
    #pragma unroll
    for (int c = 0; c < NC; ++c) {
        const float s = sigmoidf_(cp[(size_t)c * NLOC]);
        if (s > CAND_THR) {
            const unsigned bits = __float_as_uint(s * sc);
            if ((bits >> 17) >= cb) {
                const unsigned pos = atomicAdd(&counts[b], 1u);
                if (pos < CAP) {
                    const unsigned flat = (unsigned)(n * NC + c);
                    keys[(size_t)b * CAP + pos] = ((ull)bits << 32) | (unsigned)(~flat);
                }
            }
        }
    }
}

// Pass 4: exact sorted top-512 by rank-counting (keys are unique)
__global__ void select_kernel(const ull* __restrict__ keys,
                              const unsigned int* __restrict__ counts,
                              ull* __restrict__ topk) {
    __shared__ ull tile[512];
    const int b = blockIdx.y;
    const int M = (int)min(counts[b], (unsigned)CAP);
    const int e = blockIdx.x * blockDim.x + threadIdx.x;
    const ull ke = (e < M) ? keys[(size_t)b * CAP + e] : 0ull;
    int r = 0;
    for (int j0 = 0; j0 < M; j0 += 512) {
        const int jn = min(512, M - j0);
        __syncthreads();
        for (int i = threadIdx.x; i < jn; i += blockDim.x)
            tile[i] = keys[(size_t)b * CAP + j0 + i];
        __syncthreads();
        if (e < M)
            for (int i = 0; i < jn; ++i) r += (tile[i] > ke) ? 1 : 0;
    }
    if (e < M && r < TOPN) topk[b * TOPN + r] = ke;
}

// Pass 5: decode boxes for the top-512
__global__ void decode_kernel(const ull* __restrict__ topk,
                              const float* __restrict__ loc,
                              const float* __restrict__ box,
                              float* __restrict__ det,
                              float* __restrict__ score,
                              int* __restrict__ clsid,
                              int* __restrict__ validout) {
    const int b = blockIdx.x, t = threadIdx.x;
    const ull k = topk[b * TOPN + t];
    const unsigned bits = (unsigned)(k >> 32);
    const float val = __uint_as_float(bits);
    int valid = (val > 0.0f) ? 1 : 0;
    const unsigned flat = ~(unsigned)(k & 0xffffffffu);
    int n = 0, c = 0;
    if (valid) { n = (int)(flat >> 3); c = (int)(flat & 7u); }
    const float lx = loc[n * 3 + 0], ly = loc[n * 3 + 1], lz = loc[n * 3 + 2];
    const float* bp = box + (size_t)b * 6 * NLOC + n;
    const float b0 = bp[0];
    const float b1 = bp[(size_t)NLOC];
    const float b2 = bp[2 * (size_t)NLOC];
    const float b3 = bp[3 * (size_t)NLOC];
    const float b4 = bp[4 * (size_t)NLOC];
    const float b5 = bp[5 * (size_t)NLOC];
    const float d0 = fminf(fmaxf(lx - b0, 0.0f), 255.0f);
    const float d1 = fminf(fmaxf(ly - b1, 0.0f), 255.0f);
    const float d2 = fminf(fmaxf(lz - b2, 0.0f), 63.0f);
    const float d3 = fminf(fmaxf(lx + b3, 0.0f), 255.0f);
    const float d4 = fminf(fmaxf(ly + b4, 0.0f), 255.0f);
    const float d5 = fminf(fmaxf(lz + b5, 0.0f), 63.0f);
    if (d3 - d0 < 0.0f || d4 - d1 < 0.0f || d5 - d2 < 0.0f) valid = 0;
    const float s = (val > 0.0f) ? sqrtf(val) : 0.0f;
    const int o = b * TOPN + t;
    det[o * 6 + 0] = d0; det[o * 6 + 1] = d1; det[o * 6 + 2] = d2;
    det[o * 6 + 3] = d3; det[o * 6 + 4] = d4; det[o * 6 + 5] = d5;
    score[o] = s;
    clsid[o] = c + 1;
    validout[o] = valid;
}

// Pass 6: per-class greedy NMS (one wave per class) + top-100 emit
__global__ __launch_bounds__(512) void nms_out_kernel(const float* __restrict__ det,
                                                      const float* __restrict__ score,
                                                      const int* __restrict__ clsid,
                                                      const int* __restrict__ validin,
                                                      float* __restrict__ out) {
    __shared__ float sd[TOPN * 6];
    __shared__ float ss[TOPN];
    __shared__ int scl[TOPN];
    __shared__ volatile int keep[TOPN];
    __shared__ int clist[NC][TOPN];
    __shared__ int wcnt[NC];
    const int b = blockIdx.x, t = threadIdx.x;
    const int w = t >> 6, lane = t & 63;

    {
        const float* dp = det + (size_t)(b * TOPN) * 6;
        for (int i = t; i < TOPN * 6; i += 512) sd[i] = dp[i];
    }
    ss[t] = score[b * TOPN + t];
    scl[t] = clsid[b * TOPN + t];
    keep[t] = validin[b * TOPN + t];
    __syncthreads();

    // build ordered per-class index list (wave w handles class w+1)
    const int myclass = w + 1;
    int cnt = 0;
    for (int j0 = 0; j0 < TOPN; j0 += 64) {
        const int j = j0 + lane;
        const bool pred = (scl[j] == myclass) && (keep[j] != 0);
        const ull m = __ballot(pred);
        if (pred) {
            const int pos = cnt + __popcll(m & ((1ull << lane) - 1ull));
            clist[w][pos] = j;
        }
        cnt += __popcll(m);
    }
    __threadfence_block();

    // greedy NMS within the class (wave-synchronous; CDNA waves are lockstep)
    for (int i = 0; i < cnt; ++i) {
        const int gi = clist[w][i];
        if (!keep[gi]) continue;
        const float lx0 = sd[gi * 6 + 0], ly0 = sd[gi * 6 + 1], lz0 = sd[gi * 6 + 2];
        const float hx0 = sd[gi * 6 + 3], hy0 = sd[gi * 6 + 4], hz0 = sd[gi * 6 + 5];
        const float vol0 = fmaxf(hx0 - lx0, 0.0f) * fmaxf(hy0 - ly0, 0.0f) * fmaxf(hz0 - lz0, 0.0f);
        for (int e = i + 1 + lane; e < cnt; e += 64) {
            const int gj = clist[w][e];
            if (keep[gj]) {
                const float lx1 = sd[gj * 6 + 0], ly1 = sd[gj * 6 + 1], lz1 = sd[gj * 6 + 2];
                const float hx1 = sd[gj * 6 + 3], hy1 = sd[gj * 6 + 4], hz1 = sd[gj * 6 + 5];
                const float ix = fminf(hx0, hx1) - fmaxf(lx0, lx1);
                const float iy = fminf(hy0, hy1) - fmaxf(ly0, ly1);
                const float iz = fminf(hz0, hz1) - fmaxf(lz0, lz1);
                const float inter = fmaxf(ix, 0.0f) * fmaxf(iy, 0.0f) * fmaxf(iz, 0.0f);
                const float vol1 = fmaxf(hx1 - lx1, 0.0f) * fmaxf(hy1 - ly1, 0.0f) * fmaxf(hz1 - lz1, 0.0f);
                const float iou = inter / (vol0 + vol1 - inter + 1e-9f);
                if (iou > NMS_THR) keep[gj] = 0;
            }
        }
        __threadfence_block();
    }
    __syncthreads();

    // rank survivors in position order (positions are score-descending)
    const ull km = __ballot(keep[t] != 0);
    if (lane == 0) wcnt[w] = __popcll(km);
    __syncthreads();
    int before = 0, total = 0;
    #pragma unroll
    for (int w2 = 0; w2 < NC; ++w2) {
        total += wcnt[w2];
        if (w2 < w) before += wcnt[w2];
    }
    const int myrank = before + __popcll(km & ((1ull << lane) - 1ull));

    float* fbox = out;                       // (B,100,6)
    float* fscore = out + NB * POST * 6;     // (B,100)
    float* flabel = out + NB * POST * 7;     // (B,100)
    float* fvalid = out + NB * POST * 8;     // (B,100)

    if (keep[t] && myrank < POST) {
        #pragma unroll
        for (int k = 0; k < 6; ++k) fbox[(b * POST + myrank) * 6 + k] = sd[t * 6 + k];
        fscore[b * POST + myrank] = ss[t];
        flabel[b * POST + myrank] = (float)scl[t];
        fvalid[b * POST + myrank] = 1.0f;
    }
    const int tc = min(total, POST);
    if (t >= tc && t < POST) {
        #pragma unroll
        for (int k = 0; k < 6; ++k) fbox[(b * POST + t) * 6 + k] = 0.0f;
        fscore[b * POST + t] = 0.0f;
        flabel[b * POST + t] = 0.0f;
        fvalid[b * POST + t] = 0.0f;
    }
}

extern "C" void kernel_launch(void* const* d_in, const int* in_sizes, int n_in,
                              void* d_out, int out_size, void* d_ws, size_t ws_size,
                              hipStream_t stream) {
    const float* location = (const float*)d_in[0];
    const float* cls_pred = (const float*)d_in[1];
    const float* box_pred = (const float*)d_in[2];
    const float* ctr_pred = (const float*)d_in[3];

    char* ws = (char*)d_ws;
    unsigned int* hist   = (unsigned int*)(ws + OFF_HIST);
    unsigned int* counts = (unsigned int*)(ws + OFF_CNT);
    ull*          topk   = (ull*)(ws + OFF_TOPK);
    unsigned int* cutoff = (unsigned int*)(ws + OFF_CUT);
    ull*          keys   = (ull*)(ws + OFF_KEYS);
    float*        det    = (float*)(ws + OFF_DET);
    float*        score  = (float*)(ws + OFF_SCORE);
    int*          clsid  = (int*)(ws + OFF_CLS);
    int*          valid  = (int*)(ws + OFF_VALID);

    hipMemsetAsync(d_ws, 0, ZERO_BYTES, stream);

    dim3 sgrid(NLOC / 256, NB);
    hist_kernel<<<sgrid, 256, 0, stream>>>(cls_pred, ctr_pred, hist);
    cutoff_kernel<<<NB, 64, 0, stream>>>(hist, cutoff);
    gather_kernel<<<sgrid, 256, 0, stream>>>(cls_pred, ctr_pred, cutoff, keys, counts);
    select_kernel<<<dim3(CAP / 256, NB), 256, 0, stream>>>(keys, counts, topk);
    decode_kernel<<<NB, TOPN, 0, stream>>>(topk, location, box_pred, det, score, clsid, valid);
    nms_out_kernel<<<NB, TOPN, 0, stream>>>(det, score, clsid, valid, (float*)d_out);
}

// Round 2
// 175.167 us; speedup vs baseline: 1.5363x; 1.5363x over previous
//
#include <hip/hip_runtime.h>

#define NB 4
#define NC 8
#define NLOC 524288        // H*W*D = 128*128*32
#define TOPN 512
#define POST 100
#define NBIN 8192
#define CAP 16384
#define LCAP 2048          // per-block LDS staging capacity
#define NMS_THR 0.6f
#define CAND_THR 0.05f
#define SPEC_THR 0.5f      // speculative score threshold (> CAND_THR; implies cls_raw > 0)

typedef unsigned long long ull;

// ---------------- workspace layout ----------------
// [0, 16)        counts   : NB u32   (zeroed each call)
// [16, 32)       overflow : NB u32   (zeroed each call)
// [64, 16448)    topk     : NB*TOPN u64 (zeroed each call)
// [16448, 540736) keys    : NB*CAP u64
#define OFF_CNT    0
#define OFF_OVF    16
#define OFF_TOPK   64
#define OFF_KEYS   16448
#define ZERO_BYTES 16448

__device__ __forceinline__ float sigmoidf_(float x) {
    return 1.0f / (1.0f + expf(-x));
}

// Pass 1: single streaming pass. Sign-test cls_raw > 0 (implied by score > 0.5),
// compute sigmoids only on the rare path, stage hits in LDS, one global atomic
// per block to reserve contiguous key slots.
__global__ __launch_bounds__(256) void gather_spec(const float* __restrict__ cls,
                                                   const float* __restrict__ ctr,
                                                   ull* __restrict__ keys,
                                                   unsigned int* __restrict__ counts,
                                                   unsigned int* __restrict__ ovf) {
    __shared__ ull lkeys[LCAP];
    __shared__ unsigned int lcnt;
    __shared__ unsigned int lbase;
    const int b = blockIdx.y;
    if (threadIdx.x == 0) lcnt = 0;
    __syncthreads();

    const int n0 = (blockIdx.x * blockDim.x + threadIdx.x) * 4;
    const float4 cv = *(const float4*)(ctr + (size_t)b * NLOC + n0);
    float4 cl[NC];
    #pragma unroll
    for (int c = 0; c < NC; ++c)
        cl[c] = *(const float4*)(cls + ((size_t)b * NC + c) * NLOC + n0);

    #pragma unroll
    for (int j = 0; j < 4; ++j) {
        bool any = false;
        #pragma unroll
        for (int c = 0; c < NC; ++c) any |= (((const float*)&cl[c])[j] > 0.0f);
        if (any) {
            const float sc = sigmoidf_(((const float*)&cv)[j]);
            #pragma unroll
            for (int c = 0; c < NC; ++c) {
                const float x = ((const float*)&cl[c])[j];
                if (x > 0.0f) {
                    const float p = sigmoidf_(x) * sc;
                    if (p > SPEC_THR) {
                        const unsigned pos = atomicAdd(&lcnt, 1u);
                        if (pos < LCAP) {
                            const unsigned flat = (unsigned)((n0 + j) * NC + c);
                            lkeys[pos] = ((ull)__float_as_uint(p) << 32) | (unsigned)(~flat);
                        }
                    }
                }
            }
        }
    }
    __syncthreads();
    const unsigned m = lcnt;
    if (threadIdx.x == 0) {
        const unsigned stored = (m > LCAP) ? LCAP : m;
        lbase = atomicAdd(&counts[b], stored);
        if (m > LCAP) ovf[b] = 1;  // dropped entries -> force fallback rebuild
    }
    __syncthreads();
    const unsigned stored = (m > LCAP) ? LCAP : m;
    const unsigned base = lbase;
    for (unsigned i = threadIdx.x; i < stored; i += blockDim.x) {
        const unsigned pos = base + i;
        if (pos < CAP) keys[(size_t)b * CAP + pos] = lkeys[i];
    }
}

// Pass 2 (flag-gated, normally early-exits): exact rebuild via per-image
// histogram + cutoff + gather, one block per image. Correctness insurance only.
__global__ __launch_bounds__(1024) void fallback_kernel(const float* __restrict__ cls,
                                                        const float* __restrict__ ctr,
                                                        ull* __restrict__ keys,
                                                        unsigned int* __restrict__ counts,
                                                        const unsigned int* __restrict__ ovf) {
    __shared__ unsigned int hist[NBIN];
    __shared__ unsigned int cut_s;
    const int b = blockIdx.x;
    const unsigned cnt0 = counts[b];
    if (cnt0 >= TOPN && cnt0 <= CAP && ovf[b] == 0) return;

    for (int i = threadIdx.x; i < NBIN; i += blockDim.x) hist[i] = 0;
    __syncthreads();
    for (int n = threadIdx.x; n < NLOC; n += blockDim.x) {
        const float sc = sigmoidf_(ctr[(size_t)b * NLOC + n]);
        #pragma unroll
        for (int c = 0; c < NC; ++c) {
            const float s = sigmoidf_(cls[((size_t)b * NC + c) * NLOC + n]);
            if (s > CAND_THR) {
                const unsigned bits = __float_as_uint(s * sc);
                atomicAdd(&hist[bits >> 17], 1u);
            }
        }
    }
    __syncthreads();
    if (threadIdx.x == 0) {
        unsigned cum = 0;
        int bin = 0;
        for (int i = NBIN - 1; i >= 0; --i) {
            cum += hist[i];
            if (cum >= TOPN) { bin = i; break; }
        }
        cut_s = (unsigned)bin;
        counts[b] = 0;
    }
    __syncthreads();
    const unsigned cb = cut_s;
    for (int n = threadIdx.x; n < NLOC; n += blockDim.x) {
        const float sc = sigmoidf_(ctr[(size_t)b * NLOC + n]);
        #pragma unroll
        for (int c = 0; c < NC; ++c) {
            const float s = sigmoidf_(cls[((size_t)b * NC + c) * NLOC + n]);
            if (s > CAND_THR) {
                const unsigned bits = __float_as_uint(s * sc);
                if ((bits >> 17) >= cb) {
                    const unsigned pos = atomicAdd(&counts[b], 1u);
                    if (pos < CAP) {
                        const unsigned flat = (unsigned)(n * NC + c);
                        keys[(size_t)b * CAP + pos] = ((ull)bits << 32) | (unsigned)(~flat);
                    }
                }
            }
        }
    }
}

// Pass 3: exact sorted top-512 by rank-counting (keys are unique)
__global__ void select_kernel(const ull* __restrict__ keys,
                              const unsigned int* __restrict__ counts,
                              ull* __restrict__ topk) {
    __shared__ ull tile[512];
    const int b = blockIdx.y;
    const int M = (int)min(counts[b], (unsigned)CAP);
    const int e = blockIdx.x * blockDim.x + threadIdx.x;
    if (blockIdx.x * (int)blockDim.x >= M) return;  // block-uniform early exit
    const ull ke = (e < M) ? keys[(size_t)b * CAP + e] : 0ull;
    int r = 0;
    for (int j0 = 0; j0 < M; j0 += 512) {
        const int jn = min(512, M - j0);
        __syncthreads();
        for (int i = threadIdx.x; i < jn; i += blockDim.x)
            tile[i] = keys[(size_t)b * CAP + j0 + i];
        __syncthreads();
        if (e < M)
            for (int i = 0; i < jn; ++i) r += (tile[i] > ke) ? 1 : 0;
    }
    if (e < M && r < TOPN) topk[b * TOPN + r] = ke;
}

// Pass 4: decode + per-class greedy NMS (one wave per class) + top-100 emit
__global__ __launch_bounds__(512) void decode_nms_kernel(const ull* __restrict__ topk,
                                                         const float* __restrict__ loc,
                                                         const float* __restrict__ box,
                                                         float* __restrict__ out) {
    __shared__ float sd[TOPN * 6];
    __shared__ float ss[TOPN];
    __shared__ int scl[TOPN];
    __shared__ volatile int keep[TOPN];
    __shared__ int clist[NC][TOPN];
    __shared__ int wcnt[NC];
    const int b = blockIdx.x, t = threadIdx.x;
    const int w = t >> 6, lane = t & 63;

    // ---- decode ----
    {
        const ull k = topk[b * TOPN + t];
        const unsigned bits = (unsigned)(k >> 32);
        const float val = __uint_as_float(bits);
        int valid = (val > 0.0f) ? 1 : 0;
        const unsigned flat = ~(unsigned)(k & 0xffffffffu);
        int n = 0, c = 0;
        if (valid) { n = (int)(flat >> 3); c = (int)(flat & 7u); }
        const float lx = loc[n * 3 + 0], ly = loc[n * 3 + 1], lz = loc[n * 3 + 2];
        const float* bp = box + (size_t)b * 6 * NLOC + n;
        const float b0 = bp[0];
        const float b1 = bp[(size_t)NLOC];
        const float b2 = bp[2 * (size_t)NLOC];
        const float b3 = bp[3 * (size_t)NLOC];
        const float b4 = bp[4 * (size_t)NLOC];
        const float b5 = bp[5 * (size_t)NLOC];
        const float d0 = fminf(fmaxf(lx - b0, 0.0f), 255.0f);
        const float d1 = fminf(fmaxf(ly - b1, 0.0f), 255.0f);
        const float d2 = fminf(fmaxf(lz - b2, 0.0f), 63.0f);
        const float d3 = fminf(fmaxf(lx + b3, 0.0f), 255.0f);
        const float d4 = fminf(fmaxf(ly + b4, 0.0f), 255.0f);
        const float d5 = fminf(fmaxf(lz + b5, 0.0f), 63.0f);
        if (d3 - d0 < 0.0f || d4 - d1 < 0.0f || d5 - d2 < 0.0f) valid = 0;
        sd[t * 6 + 0] = d0; sd[t * 6 + 1] = d1; sd[t * 6 + 2] = d2;
        sd[t * 6 + 3] = d3; sd[t * 6 + 4] = d4; sd[t * 6 + 5] = d5;
        ss[t] = (val > 0.0f) ? sqrtf(val) : 0.0f;
        scl[t] = c + 1;
        keep[t] = valid;
    }
    __syncthreads();

    // ---- build ordered per-class index list (wave w handles class w+1) ----
    const int myclass = w + 1;
    int cnt = 0;
    for (int j0 = 0; j0 < TOPN; j0 += 64) {
        const int j = j0 + lane;
        const bool pred = (scl[j] == myclass) && (keep[j] != 0);
        const ull m = __ballot(pred);
        if (pred) {
            const int pos = cnt + __popcll(m & ((1ull << lane) - 1ull));
            clist[w][pos] = j;
        }
        cnt += __popcll(m);
    }
    __threadfence_block();

    // ---- greedy NMS within the class (wave-synchronous) ----
    for (int i = 0; i < cnt; ++i) {
        const int gi = clist[w][i];
        if (!keep[gi]) continue;
        const float lx0 = sd[gi * 6 + 0], ly0 = sd[gi * 6 + 1], lz0 = sd[gi * 6 + 2];
        const float hx0 = sd[gi * 6 + 3], hy0 = sd[gi * 6 + 4], hz0 = sd[gi * 6 + 5];
        const float vol0 = fmaxf(hx0 - lx0, 0.0f) * fmaxf(hy0 - ly0, 0.0f) * fmaxf(hz0 - lz0, 0.0f);
        for (int e = i + 1 + lane; e < cnt; e += 64) {
            const int gj = clist[w][e];
            if (keep[gj]) {
                const float lx1 = sd[gj * 6 + 0], ly1 = sd[gj * 6 + 1], lz1 = sd[gj * 6 + 2];
                const float hx1 = sd[gj * 6 + 3], hy1 = sd[gj * 6 + 4], hz1 = sd[gj * 6 + 5];
                const float ix = fminf(hx0, hx1) - fmaxf(lx0, lx1);
                const float iy = fminf(hy0, hy1) - fmaxf(ly0, ly1);
                const float iz = fminf(hz0, hz1) - fmaxf(lz0, lz1);
                const float inter = fmaxf(ix, 0.0f) * fmaxf(iy, 0.0f) * fmaxf(iz, 0.0f);
                const float vol1 = fmaxf(hx1 - lx1, 0.0f) * fmaxf(hy1 - ly1, 0.0f) * fmaxf(hz1 - lz1, 0.0f);
                const float iou = inter / (vol0 + vol1 - inter + 1e-9f);
                if (iou > NMS_THR) keep[gj] = 0;
            }
        }
        __threadfence_block();
    }
    __syncthreads();

    // ---- rank survivors in position order (positions are score-descending) ----
    const ull km = __ballot(keep[t] != 0);
    if (lane == 0) wcnt[w] = __popcll(km);
    __syncthreads();
    int before = 0, total = 0;
    #pragma unroll
    for (int w2 = 0; w2 < NC; ++w2) {
        total += wcnt[w2];
        if (w2 < w) before += wcnt[w2];
    }
    const int myrank = before + __popcll(km & ((1ull << lane) - 1ull));

    float* fbox = out;                       // (B,100,6)
    float* fscore = out + NB * POST * 6;     // (B,100)
    float* flabel = out + NB * POST * 7;     // (B,100)
    float* fvalid = out + NB * POST * 8;     // (B,100)

    if (keep[t] && myrank < POST) {
        #pragma unroll
        for (int k = 0; k < 6; ++k) fbox[(b * POST + myrank) * 6 + k] = sd[t * 6 + k];
        fscore[b * POST + myrank] = ss[t];
        flabel[b * POST + myrank] = (float)scl[t];
        fvalid[b * POST + myrank] = 1.0f;
    }
    const int tc = min(total, POST);
    if (t >= tc && t < POST) {
        #pragma unroll
        for (int k = 0; k < 6; ++k) fbox[(b * POST + t) * 6 + k] = 0.0f;
        fscore[b * POST + t] = 0.0f;
        flabel[b * POST + t] = 0.0f;
        fvalid[b * POST + t] = 0.0f;
    }
}

extern "C" void kernel_launch(void* const* d_in, const int* in_sizes, int n_in,
                              void* d_out, int out_size, void* d_ws, size_t ws_size,
                              hipStream_t stream) {
    const float* location = (const float*)d_in[0];
    const float* cls_pred = (const float*)d_in[1];
    const float* box_pred = (const float*)d_in[2];
    const float* ctr_pred = (const float*)d_in[3];

    char* ws = (char*)d_ws;
    unsigned int* counts = (unsigned int*)(ws + OFF_CNT);
    unsigned int* ovf    = (unsigned int*)(ws + OFF_OVF);
    ull*          topk   = (ull*)(ws + OFF_TOPK);
    ull*          keys   = (ull*)(ws + OFF_KEYS);

    hipMemsetAsync(d_ws, 0, ZERO_BYTES, stream);

    gather_spec<<<dim3(NLOC / 1024, NB), 256, 0, stream>>>(cls_pred, ctr_pred, keys, counts, ovf);
    fallback_kernel<<<NB, 1024, 0, stream>>>(cls_pred, ctr_pred, keys, counts, ovf);
    select_kernel<<<dim3(CAP / 256, NB), 256, 0, stream>>>(keys, counts, topk);
    decode_nms_kernel<<<NB, TOPN, 0, stream>>>(topk, location, box_pred, (float*)d_out);
}

// Round 3
// 100.728 us; speedup vs baseline: 2.6717x; 1.7390x over previous
//
#include <hip/hip_runtime.h>

#define NB 4
#define NC 8
#define NLOC 524288        // H*W*D = 128*128*32
#define TOPN 512
#define POST 100
#define NBIN 8192          // fallback histogram bins
#define SELBINS 4096       // select histogram bins over score bits (0.5..1.0)
#define SCAP 4096          // survivor capacity (need ~512+eps)
#define CAP 16384
#define LCAP 2048          // per-block LDS staging capacity in gather
#define NMS_THR 0.6f
#define CAND_THR 0.05f
#define SPEC_THR 0.5f      // speculative score threshold (> CAND_THR; implies cls_raw > 0)

typedef unsigned long long ull;

// ---------------- workspace layout ----------------
// [0, 16)      counts : NB u32  (zeroed each call)
// [16, 32)     ovf    : NB u32  (zeroed each call)
// [64, 524352) keys   : NB*CAP u64
#define OFF_CNT    0
#define OFF_OVF    16
#define OFF_KEYS   64
#define ZERO_BYTES 32

__device__ __forceinline__ float sigmoidf_(float x) {
    return 1.0f / (1.0f + expf(-x));
}

// Pass 1: single streaming pass. Sign-test cls_raw > 0 (implied by score > 0.5),
// compute sigmoids only on the rare path, stage hits in LDS, one global atomic
// per block to reserve contiguous key slots.
__global__ __launch_bounds__(256) void gather_spec(const float* __restrict__ cls,
                                                   const float* __restrict__ ctr,
                                                   ull* __restrict__ keys,
                                                   unsigned int* __restrict__ counts,
                                                   unsigned int* __restrict__ ovf) {
    __shared__ ull lkeys[LCAP];
    __shared__ unsigned int lcnt;
    __shared__ unsigned int lbase;
    const int b = blockIdx.y;
    if (threadIdx.x == 0) lcnt = 0;
    __syncthreads();

    const int n0 = (blockIdx.x * blockDim.x + threadIdx.x) * 4;
    const float4 cv = *(const float4*)(ctr + (size_t)b * NLOC + n0);
    float4 cl[NC];
    #pragma unroll
    for (int c = 0; c < NC; ++c)
        cl[c] = *(const float4*)(cls + ((size_t)b * NC + c) * NLOC + n0);

    #pragma unroll
    for (int j = 0; j < 4; ++j) {
        bool any = false;
        #pragma unroll
        for (int c = 0; c < NC; ++c) any |= (((const float*)&cl[c])[j] > 0.0f);
        if (any) {
            const float sc = sigmoidf_(((const float*)&cv)[j]);
            #pragma unroll
            for (int c = 0; c < NC; ++c) {
                const float x = ((const float*)&cl[c])[j];
                if (x > 0.0f) {
                    const float p = sigmoidf_(x) * sc;
                    if (p > SPEC_THR) {
                        const unsigned pos = atomicAdd(&lcnt, 1u);
                        if (pos < LCAP) {
                            const unsigned flat = (unsigned)((n0 + j) * NC + c);
                            lkeys[pos] = ((ull)__float_as_uint(p) << 32) | (unsigned)(~flat);
                        }
                    }
                }
            }
        }
    }
    __syncthreads();
    const unsigned m = lcnt;
    if (threadIdx.x == 0) {
        const unsigned stored = (m > LCAP) ? LCAP : m;
        lbase = atomicAdd(&counts[b], stored);
        if (m > LCAP) ovf[b] = 1;  // dropped entries -> force fallback rebuild
    }
    __syncthreads();
    const unsigned stored = (m > LCAP) ? LCAP : m;
    const unsigned base = lbase;
    for (unsigned i = threadIdx.x; i < stored; i += blockDim.x) {
        const unsigned pos = base + i;
        if (pos < CAP) keys[(size_t)b * CAP + pos] = lkeys[i];
    }
}

// Pass 2 (one block per image, 1024 threads): optional exact fallback rebuild,
// hierarchical top-512 select, box decode, per-class NMS, top-100 emit.
__global__ __launch_bounds__(1024) void select_nms_kernel(const float* __restrict__ cls,
                                                          const float* __restrict__ ctr,
                                                          ull* __restrict__ keys,
                                                          unsigned int* __restrict__ counts,
                                                          const unsigned int* __restrict__ ovf,
                                                          const float* __restrict__ loc,
                                                          const float* __restrict__ box,
                                                          float* __restrict__ out) {
    __shared__ union SU {
        struct { unsigned int hist[SELBINS]; ull surv[SCAP]; } sel;   // 16KB + 32KB
        unsigned int fhist[NBIN];                                     // 32KB (fallback)
        struct { float sd[TOPN * 6]; float ss[TOPN]; int scl[TOPN];
                 int keep[TOPN]; int clist[NC][TOPN]; int wcnt[NC]; } nms;  // ~34KB
    } u;
    __shared__ ull tk[TOPN];          // persists across phases (4KB)
    __shared__ unsigned int scnt;
    __shared__ int cut_s;

    const int b = blockIdx.x, t = threadIdx.x;

    // ---------- phase 0: fallback rebuild (block-uniform branch, normally skipped) ----------
    {
        const unsigned cnt0 = counts[b];
        const bool bad = !(cnt0 >= TOPN && cnt0 <= CAP && ovf[b] == 0);
        if (bad) {
            for (int i = t; i < NBIN; i += 1024) u.fhist[i] = 0;
            __syncthreads();
            for (int n = t; n < NLOC; n += 1024) {
                const float sc = sigmoidf_(ctr[(size_t)b * NLOC + n]);
                #pragma unroll
                for (int c = 0; c < NC; ++c) {
                    const float s = sigmoidf_(cls[((size_t)b * NC + c) * NLOC + n]);
                    if (s > CAND_THR) atomicAdd(&u.fhist[__float_as_uint(s * sc) >> 17], 1u);
                }
            }
            __syncthreads();
            if (t == 0) {
                unsigned cum = 0; int bin = 0;
                for (int i = NBIN - 1; i >= 0; --i) {
                    cum += u.fhist[i];
                    if (cum >= TOPN) { bin = i; break; }
                }
                cut_s = bin;
                counts[b] = 0;
            }
            __syncthreads();
            const unsigned cb2 = (unsigned)cut_s;
            for (int n = t; n < NLOC; n += 1024) {
                const float sc = sigmoidf_(ctr[(size_t)b * NLOC + n]);
                #pragma unroll
                for (int c = 0; c < NC; ++c) {
                    const float s = sigmoidf_(cls[((size_t)b * NC + c) * NLOC + n]);
                    if (s > CAND_THR) {
                        const unsigned bits = __float_as_uint(s * sc);
                        if ((bits >> 17) >= cb2) {
                            const unsigned pos = atomicAdd(&counts[b], 1u);
                            if (pos < CAP)
                                keys[(size_t)b * CAP + pos] =
                                    ((ull)bits << 32) | (unsigned)(~(unsigned)(n * NC + c));
                        }
                    }
                }
            }
        }
    }
    __syncthreads();   // also drains this block's global writes (vmcnt)

    const int M = (int)min(counts[b], (unsigned)CAP);

    // ---------- phase 1: histogram of key score bits ----------
    for (int i = t; i < SELBINS; i += 1024) u.sel.hist[i] = 0;
    if (t == 0) scnt = 0;
    if (t < TOPN) tk[t] = 0;
    __syncthreads();
    for (int i = t; i < M; i += 1024) {
        const unsigned hi = (unsigned)(keys[(size_t)b * CAP + i] >> 32);
        const int off = (int)hi - 0x3F000000;
        int bin = (off < 0) ? 0 : (off >> 11);
        if (bin > SELBINS - 1) bin = SELBINS - 1;
        atomicAdd(&u.sel.hist[bin], 1u);
    }
    __syncthreads();

    // ---------- phase 2: cutoff bin via wave-0 suffix scan ----------
    if (t < 64) {
        unsigned s = 0;
        for (int i = 0; i < 64; ++i)                       // rotated read: 2 lanes/bank
            s += u.sel.hist[t * 64 + ((i + t) & 63)];
        unsigned suf = s;
        #pragma unroll
        for (int d = 1; d < 64; d <<= 1) {
            const unsigned o = __shfl_down(suf, d);
            suf += (t + d < 64) ? o : 0u;
        }
        const ull mask = __ballot(suf >= TOPN);
        unsigned nxt = __shfl_down(suf, 1);
        if (t == 63) nxt = 0;
        if (mask == 0ull) {
            if (t == 0) cut_s = 0;
        } else {
            const int L = 63 - __builtin_clzll(mask);
            if (t == L) {
                unsigned cum = nxt;
                int c = L * 64;
                for (int i = 63; i >= 0; --i) {
                    cum += u.sel.hist[L * 64 + i];
                    if (cum >= TOPN) { c = L * 64 + i; break; }
                }
                cut_s = c;
            }
        }
    }
    __syncthreads();

    // ---------- phase 3: compact survivors (bins >= cutoff) ----------
    const int cb = cut_s;
    for (int i = t; i < M; i += 1024) {
        const ull k = keys[(size_t)b * CAP + i];
        const unsigned hi = (unsigned)(k >> 32);
        const int off = (int)hi - 0x3F000000;
        int bin = (off < 0) ? 0 : (off >> 11);
        if (bin > SELBINS - 1) bin = SELBINS - 1;
        if (bin >= cb) {
            const unsigned p = atomicAdd(&scnt, 1u);
            if (p < SCAP) u.sel.surv[p] = k;
        }
    }
    __syncthreads();

    // ---------- phase 4: exact rank-count among survivors ----------
    const unsigned sc_final = scnt;
    if (sc_final <= (unsigned)SCAP) {
        const int S = (int)sc_final;
        for (int i = t; i < S; i += 1024) {
            const ull ke = u.sel.surv[i];
            int r = 0;
            for (int j = 0; j < S; ++j) r += (u.sel.surv[j] > ke) ? 1 : 0;
            if (r < TOPN) tk[r] = ke;
        }
    } else {
        // pathological tie storm: exact global rank-count (never on this data)
        for (int i = t; i < M; i += 1024) {
            const ull ke = keys[(size_t)b * CAP + i];
            int r = 0;
            for (int j = 0; j < M; ++j) r += (keys[(size_t)b * CAP + j] > ke) ? 1 : 0;
            if (r < TOPN) tk[r] = ke;
        }
    }
    __syncthreads();

    // ---------- phase 5: decode (t < 512) ----------
    volatile int* keep = u.nms.keep;
    if (t < TOPN) {
        const ull k = tk[t];
        const unsigned bits = (unsigned)(k >> 32);
        const float val = __uint_as_float(bits);
        int valid = (val > 0.0f) ? 1 : 0;
        const unsigned flat = ~(unsigned)(k & 0xffffffffu);
        int n = 0, c = 0;
        if (valid) { n = (int)(flat >> 3); c = (int)(flat & 7u); }
        const float lx = loc[n * 3 + 0], ly = loc[n * 3 + 1], lz = loc[n * 3 + 2];
        const float* bp = box + (size_t)b * 6 * NLOC + n;
        const float b0 = bp[0];
        const float b1 = bp[(size_t)NLOC];
        const float b2 = bp[2 * (size_t)NLOC];
        const float b3 = bp[3 * (size_t)NLOC];
        const float b4 = bp[4 * (size_t)NLOC];
        const float b5 = bp[5 * (size_t)NLOC];
        const float d0 = fminf(fmaxf(lx - b0, 0.0f), 255.0f);
        const float d1 = fminf(fmaxf(ly - b1, 0.0f), 255.0f);
        const float d2 = fminf(fmaxf(lz - b2, 0.0f), 63.0f);
        const float d3 = fminf(fmaxf(lx + b3, 0.0f), 255.0f);
        const float d4 = fminf(fmaxf(ly + b4, 0.0f), 255.0f);
        const float d5 = fminf(fmaxf(lz + b5, 0.0f), 63.0f);
        if (d3 - d0 < 0.0f || d4 - d1 < 0.0f || d5 - d2 < 0.0f) valid = 0;
        u.nms.sd[t * 6 + 0] = d0; u.nms.sd[t * 6 + 1] = d1; u.nms.sd[t * 6 + 2] = d2;
        u.nms.sd[t * 6 + 3] = d3; u.nms.sd[t * 6 + 4] = d4; u.nms.sd[t * 6 + 5] = d5;
        u.nms.ss[t] = (val > 0.0f) ? sqrtf(val) : 0.0f;
        u.nms.scl[t] = c + 1;
        keep[t] = valid;
    }
    __syncthreads();

    // ---------- phase 6: per-class greedy NMS (wave w handles class w+1) ----------
    if (t < TOPN) {
        const int w = t >> 6, lane = t & 63;
        const int myclass = w + 1;
        const float* sd = u.nms.sd;
        int cnt = 0;
        for (int j0 = 0; j0 < TOPN; j0 += 64) {
            const int j = j0 + lane;
            const bool pred = (u.nms.scl[j] == myclass) && (keep[j] != 0);
            const ull m = __ballot(pred);
            if (pred) {
                const int pos = cnt + __popcll(m & ((1ull << lane) - 1ull));
                u.nms.clist[w][pos] = j;
            }
            cnt += __popcll(m);
        }
        __threadfence_block();

        for (int i = 0; i < cnt; ++i) {
            const int gi = u.nms.clist[w][i];
            if (!keep[gi]) continue;
            const float lx0 = sd[gi * 6 + 0], ly0 = sd[gi * 6 + 1], lz0 = sd[gi * 6 + 2];
            const float hx0 = sd[gi * 6 + 3], hy0 = sd[gi * 6 + 4], hz0 = sd[gi * 6 + 5];
            const float vol0 = fmaxf(hx0 - lx0, 0.0f) * fmaxf(hy0 - ly0, 0.0f) * fmaxf(hz0 - lz0, 0.0f);
            for (int e = i + 1 + lane; e < cnt; e += 64) {
                const int gj = u.nms.clist[w][e];
                if (keep[gj]) {
                    const float lx1 = sd[gj * 6 + 0], ly1 = sd[gj * 6 + 1], lz1 = sd[gj * 6 + 2];
                    const float hx1 = sd[gj * 6 + 3], hy1 = sd[gj * 6 + 4], hz1 = sd[gj * 6 + 5];
                    const float ix = fminf(hx0, hx1) - fmaxf(lx0, lx1);
                    const float iy = fminf(hy0, hy1) - fmaxf(ly0, ly1);
                    const float iz = fminf(hz0, hz1) - fmaxf(lz0, lz1);
                    const float inter = fmaxf(ix, 0.0f) * fmaxf(iy, 0.0f) * fmaxf(iz, 0.0f);
                    const float vol1 = fmaxf(hx1 - lx1, 0.0f) * fmaxf(hy1 - ly1, 0.0f) * fmaxf(hz1 - lz1, 0.0f);
                    const float iou = inter / (vol0 + vol1 - inter + 1e-9f);
                    if (iou > NMS_THR) keep[gj] = 0;
                }
            }
            __threadfence_block();
        }
    }
    __syncthreads();

    // ---------- phase 7: rank survivors in position order, emit top-100 ----------
    if (t < TOPN) {
        const int w = t >> 6, lane = t & 63;
        const ull km = __ballot(keep[t] != 0);
        if (lane == 0) u.nms.wcnt[w] = __popcll(km);
        __threadfence_block();
        // (all waves write wcnt before any wave reads: need block sync below)
        // store per-thread ballot info for after the barrier
        // myrank computed after __syncthreads outside
        // stash km popcount prefix in a register via recompute after sync
        // -> do the sync at top level:
        // fallthrough
        (void)km;
    }
    __syncthreads();
    if (t < TOPN) {
        const int w = t >> 6, lane = t & 63;
        const ull km = __ballot(keep[t] != 0);
        int before = 0, total = 0;
        #pragma unroll
        for (int w2 = 0; w2 < NC; ++w2) {
            total += u.nms.wcnt[w2];
            if (w2 < w) before += u.nms.wcnt[w2];
        }
        const int myrank = before + __popcll(km & ((1ull << lane) - 1ull));

        float* fbox = out;                       // (B,100,6)
        float* fscore = out + NB * POST * 6;     // (B,100)
        float* flabel = out + NB * POST * 7;     // (B,100)
        float* fvalid = out + NB * POST * 8;     // (B,100)

        if (keep[t] && myrank < POST) {
            #pragma unroll
            for (int k = 0; k < 6; ++k) fbox[(b * POST + myrank) * 6 + k] = u.nms.sd[t * 6 + k];
            fscore[b * POST + myrank] = u.nms.ss[t];
            flabel[b * POST + myrank] = (float)u.nms.scl[t];
            fvalid[b * POST + myrank] = 1.0f;
        }
        const int tc = (total < POST) ? total : POST;
        if (t >= tc && t < POST) {
            #pragma unroll
            for (int k = 0; k < 6; ++k) fbox[(b * POST + t) * 6 + k] = 0.0f;
            fscore[b * POST + t] = 0.0f;
            flabel[b * POST + t] = 0.0f;
            fvalid[b * POST + t] = 0.0f;
        }
    }
}

extern "C" void kernel_launch(void* const* d_in, const int* in_sizes, int n_in,
                              void* d_out, int out_size, void* d_ws, size_t ws_size,
                              hipStream_t stream) {
    const float* location = (const float*)d_in[0];
    const float* cls_pred = (const float*)d_in[1];
    const float* box_pred = (const float*)d_in[2];
    const float* ctr_pred = (const float*)d_in[3];

    char* ws = (char*)d_ws;
    unsigned int* counts = (unsigned int*)(ws + OFF_CNT);
    unsigned int* ovf    = (unsigned int*)(ws + OFF_OVF);
    ull*          keys   = (ull*)(ws + OFF_KEYS);

    hipMemsetAsync(d_ws, 0, ZERO_BYTES, stream);

    gather_spec<<<dim3(NLOC / 1024, NB), 256, 0, stream>>>(cls_pred, ctr_pred, keys, counts, ovf);
    select_nms_kernel<<<NB, 1024, 0, stream>>>(cls_pred, ctr_pred, keys, counts, ovf,
                                               location, box_pred, (float*)d_out);
}

// Round 4
// 85.956 us; speedup vs baseline: 3.1309x; 1.1719x over previous
//
#include <hip/hip_runtime.h>

#define NB 4
#define NC 8
#define NLOC 524288        // H*W*D = 128*128*32
#define TOPN 512
#define POST 100
#define NBIN 8192          // fallback histogram bins
#define SELBINS 4096       // select histogram bins over score bits (0.5..1.0)
#define SCAP 4096          // survivor capacity (need ~512+eps)
#define CAP 16384
#define KPT 16             // keys per thread in registers (1024*16 = CAP)
#define LCAP 2048          // per-block LDS staging capacity in gather
#define NMS_THR 0.6f
#define CAND_THR 0.05f
#define SPEC_THR 0.5f      // speculative score threshold (> CAND_THR; implies cls_raw > 0)

typedef unsigned long long ull;

// ---------------- workspace layout ----------------
// [0, 16)      counts : NB u32  (zeroed each call)
// [16, 32)     ovf    : NB u32  (zeroed each call)
// [64, 524352) keys   : NB*CAP u64 (entries >= counts[b] are stale -> always index-guard)
#define OFF_CNT    0
#define OFF_OVF    16
#define OFF_KEYS   64
#define ZERO_BYTES 32

// fast sigmoid: v_exp_f32-based. ~2ulp; selection self-consistent (keys carry
// these bits), top-512/NMS ordering gaps ~1e-3 >> 1e-7 error.
__device__ __forceinline__ float sigmoidf_(float x) {
    return 1.0f / (1.0f + __expf(-x));
}

// Pass 1: single streaming pass, 8 locations/thread (18 loads in flight).
// Sign-test cls_raw > 0 (implied by score > 0.5); sigmoid only on hits.
__global__ __launch_bounds__(256) void gather_spec(const float* __restrict__ cls,
                                                   const float* __restrict__ ctr,
                                                   ull* __restrict__ keys,
                                                   unsigned int* __restrict__ counts,
                                                   unsigned int* __restrict__ ovf) {
    __shared__ ull lkeys[LCAP];
    __shared__ unsigned int lcnt;
    __shared__ unsigned int lbase;
    const int b = blockIdx.y;
    if (threadIdx.x == 0) lcnt = 0;
    __syncthreads();

    const int n0 = (blockIdx.x * blockDim.x + threadIdx.x) * 8;
    const float4* cvp = (const float4*)(ctr + (size_t)b * NLOC + n0);
    const float4 cv0 = cvp[0], cv1 = cvp[1];
    float4 cl0[NC], cl1[NC];
    #pragma unroll
    for (int c = 0; c < NC; ++c) {
        const float4* p = (const float4*)(cls + ((size_t)b * NC + c) * NLOC + n0);
        cl0[c] = p[0];
        cl1[c] = p[1];
    }

    #pragma unroll
    for (int h = 0; h < 2; ++h) {
        const float4 cv = h ? cv1 : cv0;
        #pragma unroll
        for (int j = 0; j < 4; ++j) {
            bool any = false;
            #pragma unroll
            for (int c = 0; c < NC; ++c) {
                const float x = h ? ((const float*)&cl1[c])[j] : ((const float*)&cl0[c])[j];
                any |= (x > 0.0f);
            }
            if (any) {
                const float sc = sigmoidf_(((const float*)&cv)[j]);
                #pragma unroll
                for (int c = 0; c < NC; ++c) {
                    const float x = h ? ((const float*)&cl1[c])[j] : ((const float*)&cl0[c])[j];
                    if (x > 0.0f) {
                        const float p = sigmoidf_(x) * sc;
                        if (p > SPEC_THR) {
                            const unsigned pos = atomicAdd(&lcnt, 1u);
                            if (pos < LCAP) {
                                const unsigned flat = (unsigned)((n0 + h * 4 + j) * NC + c);
                                lkeys[pos] = ((ull)__float_as_uint(p) << 32) | (unsigned)(~flat);
                            }
                        }
                    }
                }
            }
        }
    }
    __syncthreads();
    const unsigned m = lcnt;
    if (threadIdx.x == 0) {
        const unsigned stored = (m > LCAP) ? LCAP : m;
        lbase = atomicAdd(&counts[b], stored);
        if (m > LCAP) ovf[b] = 1;
    }
    __syncthreads();
    const unsigned stored = (m > LCAP) ? LCAP : m;
    const unsigned base = lbase;
    for (unsigned i = threadIdx.x; i < stored; i += blockDim.x) {
        const unsigned pos = base + i;
        if (pos < CAP) keys[(size_t)b * CAP + pos] = lkeys[i];
    }
}

__device__ __forceinline__ float iou3d_(const float* a, const float* bx) {
    const float ix = fminf(a[3], bx[3]) - fmaxf(a[0], bx[0]);
    const float iy = fminf(a[4], bx[4]) - fmaxf(a[1], bx[1]);
    const float iz = fminf(a[5], bx[5]) - fmaxf(a[2], bx[2]);
    const float inter = fmaxf(ix, 0.0f) * fmaxf(iy, 0.0f) * fmaxf(iz, 0.0f);
    const float v0 = fmaxf(a[3] - a[0], 0.0f) * fmaxf(a[4] - a[1], 0.0f) * fmaxf(a[5] - a[2], 0.0f);
    const float v1 = fmaxf(bx[3] - bx[0], 0.0f) * fmaxf(bx[4] - bx[1], 0.0f) * fmaxf(bx[5] - bx[2], 0.0f);
    return inter / (v0 + v1 - inter + 1e-9f);
}

// Pass 2 (one block/image, 1024 threads): optional fallback rebuild, register-
// resident top-512 select, decode, register NMS, top-100 emit.
__global__ __launch_bounds__(1024) void select_nms_kernel(const float* __restrict__ cls,
                                                          const float* __restrict__ ctr,
                                                          ull* __restrict__ keys,
                                                          unsigned int* __restrict__ counts,
                                                          const unsigned int* __restrict__ ovf,
                                                          const float* __restrict__ loc,
                                                          const float* __restrict__ box,
                                                          float* __restrict__ out) {
    __shared__ union SU {
        struct { unsigned int hist[SELBINS]; ull surv[SCAP]; } sel;   // 48KB
        unsigned int fhist[NBIN];                                     // 32KB (fallback)
        struct { float sd[TOPN * 6]; float ss[TOPN]; int scl[TOPN];
                 int keep[TOPN]; int clist[NC][TOPN]; int wcnt[NC]; } nms;  // ~34KB
    } u;
    __shared__ ull tk[TOPN];
    __shared__ unsigned int scnt;
    __shared__ int cut_s;

    const int b = blockIdx.x, t = threadIdx.x;

    // ---------- phase 0: fallback rebuild (block-uniform, normally skipped) ----------
    {
        const unsigned cnt0 = counts[b];
        const bool bad = !(cnt0 >= TOPN && cnt0 <= CAP && ovf[b] == 0);
        if (bad) {
            for (int i = t; i < NBIN; i += 1024) u.fhist[i] = 0;
            __syncthreads();
            for (int n = t; n < NLOC; n += 1024) {
                const float sc = sigmoidf_(ctr[(size_t)b * NLOC + n]);
                #pragma unroll
                for (int c = 0; c < NC; ++c) {
                    const float s = sigmoidf_(cls[((size_t)b * NC + c) * NLOC + n]);
                    if (s > CAND_THR) atomicAdd(&u.fhist[__float_as_uint(s * sc) >> 17], 1u);
                }
            }
            __syncthreads();
            if (t == 0) {
                unsigned cum = 0; int bin = 0;
                for (int i = NBIN - 1; i >= 0; --i) {
                    cum += u.fhist[i];
                    if (cum >= TOPN) { bin = i; break; }
                }
                cut_s = bin;
                counts[b] = 0;
            }
            __syncthreads();
            const unsigned cb2 = (unsigned)cut_s;
            for (int n = t; n < NLOC; n += 1024) {
                const float sc = sigmoidf_(ctr[(size_t)b * NLOC + n]);
                #pragma unroll
                for (int c = 0; c < NC; ++c) {
                    const float s = sigmoidf_(cls[((size_t)b * NC + c) * NLOC + n]);
                    if (s > CAND_THR) {
                        const unsigned bits = __float_as_uint(s * sc);
                        if ((bits >> 17) >= cb2) {
                            const unsigned pos = atomicAdd(&counts[b], 1u);
                            if (pos < CAP)
                                keys[(size_t)b * CAP + pos] =
                                    ((ull)bits << 32) | (unsigned)(~(unsigned)(n * NC + c));
                        }
                    }
                }
            }
            __threadfence();
        }
    }
    __syncthreads();

    const int M = (int)min(counts[b], (unsigned)CAP);

    // ---------- phase 1: load ALL keys into registers (one global pass) ----------
    ull kr[KPT];
    {
        const ulonglong2* kb = (const ulonglong2*)(keys + (size_t)b * CAP);
        #pragma unroll
        for (int p = 0; p < KPT / 2; ++p) {
            const ulonglong2 v = kb[p * 1024 + t];   // elements 2*(p*1024+t), +1
            kr[2 * p] = v.x;
            kr[2 * p + 1] = v.y;
        }
    }

    // ---------- phase 2: histogram of key score bits ----------
    for (int i = t; i < SELBINS; i += 1024) u.sel.hist[i] = 0;
    if (t == 0) scnt = 0;
    if (t < TOPN) tk[t] = 0;
    __syncthreads();
    #pragma unroll
    for (int p = 0; p < KPT / 2; ++p) {
        #pragma unroll
        for (int q = 0; q < 2; ++q) {
            const int i = 2 * (p * 1024 + t) + q;
            if (i < M) {
                const unsigned hi = (unsigned)(kr[2 * p + q] >> 32);
                const int off = (int)hi - 0x3F000000;
                int bin = (off < 0) ? 0 : (off >> 11);
                if (bin > SELBINS - 1) bin = SELBINS - 1;
                atomicAdd(&u.sel.hist[bin], 1u);
            }
        }
    }
    __syncthreads();

    // ---------- phase 3: cutoff bin via wave-0 suffix scan ----------
    if (t < 64) {
        unsigned s = 0;
        for (int i = 0; i < 64; ++i)
            s += u.sel.hist[t * 64 + ((i + t) & 63)];   // rotated: no bank pile-up
        unsigned suf = s;
        #pragma unroll
        for (int d = 1; d < 64; d <<= 1) {
            const unsigned o = __shfl_down(suf, d);
            suf += (t + d < 64) ? o : 0u;
        }
        const ull mask = __ballot(suf >= TOPN);
        unsigned nxt = __shfl_down(suf, 1);
        if (t == 63) nxt = 0;
        if (mask == 0ull) {
            if (t == 0) cut_s = 0;
        } else {
            const int L = 63 - __builtin_clzll(mask);
            if (t == L) {
                unsigned cum = nxt;
                int c = L * 64;
                for (int i = 63; i >= 0; --i) {
                    cum += u.sel.hist[L * 64 + i];
                    if (cum >= TOPN) { c = L * 64 + i; break; }
                }
                cut_s = c;
            }
        }
    }
    __syncthreads();

    // ---------- phase 4: compact survivors (bins >= cutoff) from registers ----------
    const int cb = cut_s;
    #pragma unroll
    for (int p = 0; p < KPT / 2; ++p) {
        #pragma unroll
        for (int q = 0; q < 2; ++q) {
            const int i = 2 * (p * 1024 + t) + q;
            if (i < M) {
                const ull k = kr[2 * p + q];
                const unsigned hi = (unsigned)(k >> 32);
                const int off = (int)hi - 0x3F000000;
                int bin = (off < 0) ? 0 : (off >> 11);
                if (bin > SELBINS - 1) bin = SELBINS - 1;
                if (bin >= cb) {
                    const unsigned p2 = atomicAdd(&scnt, 1u);
                    if (p2 < SCAP) u.sel.surv[p2] = k;
                }
            }
        }
    }
    __syncthreads();

    // ---------- phase 5: exact rank-count among survivors ----------
    const unsigned sc_final = scnt;
    if (sc_final <= (unsigned)SCAP) {
        const int S = (int)sc_final;
        for (int i = t; i < S; i += 1024) {
            const ull ke = u.sel.surv[i];
            int r = 0;
            for (int j = 0; j < S; ++j) r += (u.sel.surv[j] > ke) ? 1 : 0;
            if (r < TOPN) tk[r] = ke;
        }
    } else {
        // pathological tie storm: exact global rank-count (never on this data)
        for (int i = t; i < M; i += 1024) {
            const ull ke = keys[(size_t)b * CAP + i];
            int r = 0;
            for (int j = 0; j < M; ++j) r += (keys[(size_t)b * CAP + j] > ke) ? 1 : 0;
            if (r < TOPN) tk[r] = ke;
        }
    }
    __syncthreads();

    // ---------- phase 6: decode (t < 512) ----------
    if (t < TOPN) {
        const ull k = tk[t];
        const unsigned bits = (unsigned)(k >> 32);
        const float val = __uint_as_float(bits);
        int valid = (val > 0.0f) ? 1 : 0;
        const unsigned flat = ~(unsigned)(k & 0xffffffffu);
        int n = 0, c = 0;
        if (valid) { n = (int)(flat >> 3); c = (int)(flat & 7u); }
        const float lx = loc[n * 3 + 0], ly = loc[n * 3 + 1], lz = loc[n * 3 + 2];
        const float* bp = box + (size_t)b * 6 * NLOC + n;
        const float b0 = bp[0];
        const float b1 = bp[(size_t)NLOC];
        const float b2 = bp[2 * (size_t)NLOC];
        const float b3 = bp[3 * (size_t)NLOC];
        const float b4 = bp[4 * (size_t)NLOC];
        const float b5 = bp[5 * (size_t)NLOC];
        const float d0 = fminf(fmaxf(lx - b0, 0.0f), 255.0f);
        const float d1 = fminf(fmaxf(ly - b1, 0.0f), 255.0f);
        const float d2 = fminf(fmaxf(lz - b2, 0.0f), 63.0f);
        const float d3 = fminf(fmaxf(lx + b3, 0.0f), 255.0f);
        const float d4 = fminf(fmaxf(ly + b4, 0.0f), 255.0f);
        const float d5 = fminf(fmaxf(lz + b5, 0.0f), 63.0f);
        if (d3 - d0 < 0.0f || d4 - d1 < 0.0f || d5 - d2 < 0.0f) valid = 0;
        u.nms.sd[t * 6 + 0] = d0; u.nms.sd[t * 6 + 1] = d1; u.nms.sd[t * 6 + 2] = d2;
        u.nms.sd[t * 6 + 3] = d3; u.nms.sd[t * 6 + 4] = d4; u.nms.sd[t * 6 + 5] = d5;
        u.nms.ss[t] = (val > 0.0f) ? sqrtf(val) : 0.0f;
        u.nms.scl[t] = c + 1;
        u.nms.keep[t] = valid;
    }
    __syncthreads();

    // ---------- phase 7: per-class greedy NMS (wave w = class w+1) ----------
    if (t < TOPN) {
        const int w = t >> 6, lane = t & 63;
        const int myclass = w + 1;
        int cnt = 0;
        for (int j0 = 0; j0 < TOPN; j0 += 64) {
            const int j = j0 + lane;
            const bool pred = (u.nms.scl[j] == myclass) && (u.nms.keep[j] != 0);
            const ull m = __ballot(pred);
            if (pred) {
                const int pos = cnt + __popcll(m & ((1ull << lane) - 1ull));
                u.nms.clist[w][pos] = j;
            }
            cnt += __popcll(m);
        }
        __threadfence_block();

        if (cnt <= 128) {
            // register path: lane owns entries lane (set0) and lane+64 (set1)
            const int g0 = (lane < cnt) ? u.nms.clist[w][lane] : -1;
            const int g1 = (lane + 64 < cnt) ? u.nms.clist[w][lane + 64] : -1;
            float B0[6], B1[6];
            #pragma unroll
            for (int q = 0; q < 6; ++q) {
                B0[q] = (g0 >= 0) ? u.nms.sd[g0 * 6 + q] : 0.0f;
                B1[q] = (g1 >= 0) ? u.nms.sd[g1 * 6 + q] : 0.0f;
            }
            bool a0 = (g0 >= 0), a1 = (g1 >= 0);
            ull m0 = __ballot(a0), m1 = __ballot(a1);
            for (int i = 0; i < cnt; ++i) {
                const int ki = i >> 6, li = i & 63;
                const ull mi = ki ? m1 : m0;
                if (!((mi >> li) & 1ull)) continue;   // wave-uniform skip
                float pb[6];
                #pragma unroll
                for (int q = 0; q < 6; ++q) pb[q] = __shfl(ki ? B1[q] : B0[q], li);
                if (a0 && lane > i)      { if (iou3d_(B0, pb) > NMS_THR) a0 = false; }
                if (a1 && lane + 64 > i) { if (iou3d_(B1, pb) > NMS_THR) a1 = false; }
                m0 = __ballot(a0); m1 = __ballot(a1);
            }
            if (g0 >= 0 && !a0) u.nms.keep[g0] = 0;
            if (g1 >= 0 && !a1) u.nms.keep[g1] = 0;
        } else {
            // general LDS path (adversarial class skew only)
            volatile int* vkeep = u.nms.keep;
            const float* sd = u.nms.sd;
            for (int i = 0; i < cnt; ++i) {
                const int gi = u.nms.clist[w][i];
                if (!vkeep[gi]) continue;
                float pb[6];
                #pragma unroll
                for (int q = 0; q < 6; ++q) pb[q] = sd[gi * 6 + q];
                for (int e = i + 1 + lane; e < cnt; e += 64) {
                    const int gj = u.nms.clist[w][e];
                    if (vkeep[gj]) {
                        float cb_[6];
                        #pragma unroll
                        for (int q = 0; q < 6; ++q) cb_[q] = sd[gj * 6 + q];
                        if (iou3d_(cb_, pb) > NMS_THR) vkeep[gj] = 0;
                    }
                }
                __threadfence_block();
            }
        }
    }
    __syncthreads();

    // ---------- phase 8: rank survivors in position order, emit top-100 ----------
    if (t < TOPN) {
        const int w = t >> 6, lane = t & 63;
        const ull km = __ballot(u.nms.keep[t] != 0);
        if (lane == 0) u.nms.wcnt[w] = __popcll(km);
    }
    __syncthreads();
    if (t < TOPN) {
        const int w = t >> 6, lane = t & 63;
        const ull km = __ballot(u.nms.keep[t] != 0);
        int before = 0, total = 0;
        #pragma unroll
        for (int w2 = 0; w2 < NC; ++w2) {
            total += u.nms.wcnt[w2];
            if (w2 < w) before += u.nms.wcnt[w2];
        }
        const int myrank = before + __popcll(km & ((1ull << lane) - 1ull));

        float* fbox = out;                       // (B,100,6)
        float* fscore = out + NB * POST * 6;     // (B,100)
        float* flabel = out + NB * POST * 7;     // (B,100)
        float* fvalid = out + NB * POST * 8;     // (B,100)

        if (u.nms.keep[t] && myrank < POST) {
            #pragma unroll
            for (int k = 0; k < 6; ++k) fbox[(b * POST + myrank) * 6 + k] = u.nms.sd[t * 6 + k];
            fscore[b * POST + myrank] = u.nms.ss[t];
            flabel[b * POST + myrank] = (float)u.nms.scl[t];
            fvalid[b * POST + myrank] = 1.0f;
        }
        const int tc = (total < POST) ? total : POST;
        if (t >= tc && t < POST) {
            #pragma unroll
            for (int k = 0; k < 6; ++k) fbox[(b * POST + t) * 6 + k] = 0.0f;
            fscore[b * POST + t] = 0.0f;
            flabel[b * POST + t] = 0.0f;
            fvalid[b * POST + t] = 0.0f;
        }
    }
}

extern "C" void kernel_launch(void* const* d_in, const int* in_sizes, int n_in,
                              void* d_out, int out_size, void* d_ws, size_t ws_size,
                              hipStream_t stream) {
    const float* location = (const float*)d_in[0];
    const float* cls_pred = (const float*)d_in[1];
    const float* box_pred = (const float*)d_in[2];
    const float* ctr_pred = (const float*)d_in[3];

    char* ws = (char*)d_ws;
    unsigned int* counts = (unsigned int*)(ws + OFF_CNT);
    unsigned int* ovf    = (unsigned int*)(ws + OFF_OVF);
    ull*          keys   = (ull*)(ws + OFF_KEYS);

    hipMemsetAsync(d_ws, 0, ZERO_BYTES, stream);

    gather_spec<<<dim3(NLOC / 2048, NB), 256, 0, stream>>>(cls_pred, ctr_pred, keys, counts, ovf);
    select_nms_kernel<<<NB, 1024, 0, stream>>>(cls_pred, ctr_pred, keys, counts, ovf,
                                               location, box_pred, (float*)d_out);
}